// Round 2
// baseline (138.202 us; speedup 1.0000x reference)
//
#include <hip/hip_runtime.h>

#define TPB 1024

// Entire GNN fused into one workgroup of 16 waves. Only x[0] matters
// (reference takes stacked[0]); total real work ~1 MFLOP over ~450 KB of
// weights. All matmuls are "read-once": each weight element is loaded from
// global exactly once and reused across all nodes in registers.
__global__ __launch_bounds__(TPB, 4) void gnn_fused(
    const float* __restrict__ x,
    const float* __restrict__ lW1, const float* __restrict__ lb1,
    const float* __restrict__ lW2, const float* __restrict__ lb2,
    const float* __restrict__ mW1, const float* __restrict__ mb1,
    const float* __restrict__ mW2, const float* __restrict__ mb2,
    const float* __restrict__ jW1, const float* __restrict__ jb1,
    const float* __restrict__ jW2, const float* __restrict__ jb2,
    const float* __restrict__ hW1, const float* __restrict__ hb1,
    const float* __restrict__ hW2, const float* __restrict__ hb2,
    const float* __restrict__ a1Wi, const float* __restrict__ a1Wr, const float* __restrict__ a1b,
    const float* __restrict__ a2Wi, const float* __restrict__ a2Wr, const float* __restrict__ a2b,
    const float* __restrict__ cW1, const float* __restrict__ cb1,
    const float* __restrict__ cW2, const float* __restrict__ cb2,
    const int* __restrict__ eidx,
    float* __restrict__ out)
{
    const int tid = threadIdx.x;
    const int lane = tid & 63;

    __shared__ float xin[28];
    __shared__ float hid[7][64];      // MLP hidden activations
    __shared__ float node_[7][128];   // node features / ARMA state
    __shared__ float t1[7][128];      // node @ Wi
    __shared__ float t2[7][128];      // node @ Wr
    __shared__ float nrm[14];
    __shared__ int   esrc[14], edst[14];
    __shared__ float pooled[128];
    __shared__ float scratch[7168];   // 28 KB k-split partials (reused per phase)

    // ---- P0: tiny input loads
    if (tid < 28) xin[tid] = x[tid];                    // row 0 of x only
    if (tid >= 64 && tid < 78) {
        int e = tid - 64;
        esrc[e] = eidx[e]; edst[e] = eidx[14 + e];
    }
    __syncthreads();

    // ---- P1: MLP hidden layer (7x64 items) + gcn_norm (14 items) in parallel
    if (tid < 448) {
        int n = tid >> 6, j = tid & 63;                 // n wave-uniform
        const float *W1, *b1; int din, off;
        if (n == 0)      { W1 = lW1; b1 = lb1; din = 3; off = 0;  }
        else if (n == 1) { W1 = mW1; b1 = mb1; din = 2; off = 3;  }
        else if (n <= 5) { W1 = jW1; b1 = jb1; din = 4; off = 5 + 4 * (n - 2); }
        else             { W1 = hW1; b1 = hb1; din = 7; off = 21; }
        float s = b1[j];
        for (int d = 0; d < din; ++d) s = fmaf(xin[off + d], W1[d * 64 + j], s);
        hid[n][j] = fmaxf(s, 0.0f);
    } else if (tid >= 960 && tid < 974) {
        // norm[e] = deg(src)^-.5 * deg(dst)^-.5 (deg over dst, self-loops off)
        int e = tid - 960;
        int s = esrc[e], d = edst[e], cs = 0, cd = 0;
        for (int j = 0; j < 14; ++j) { cs += (edst[j] == s); cd += (edst[j] == d); }
        nrm[e] = (1.0f / sqrtf((float)cs)) * (1.0f / sqrtf((float)cd));
    }
    __syncthreads();

    // ---- P2: MLP output layer, read-once. 4 unique W2 mats x 64 col-pairs x 4 k-splits
    {
        int mat = tid >> 8;                              // wave-uniform (4 waves/mat)
        int t8  = tid & 255;
        int ks  = t8 >> 6;                               // 0..3 (16 k each)
        int c   = (t8 & 63) * 2;
        int k0  = ks * 16;
        const float* W2; int n0, nc;
        if (mat == 0)      { W2 = lW2; n0 = 0; nc = 1; }
        else if (mat == 1) { W2 = mW2; n0 = 1; nc = 1; }
        else if (mat == 2) { W2 = jW2; n0 = 2; nc = 4; }   // jets share weights
        else               { W2 = hW2; n0 = 6; nc = 1; }
        float ax[4] = {0.f,0.f,0.f,0.f}, ay[4] = {0.f,0.f,0.f,0.f};
        #pragma unroll 4
        for (int kk = 0; kk < 16; ++kk) {
            int k = k0 + kk;
            float2 wv = *(const float2*)&W2[k * 128 + c];
            #pragma unroll
            for (int q = 0; q < 4; ++q) {                // static idx, predicated
                if (q < nc) {
                    float h = hid[n0 + q][k];
                    ax[q] = fmaf(h, wv.x, ax[q]);
                    ay[q] = fmaf(h, wv.y, ay[q]);
                }
            }
        }
        #pragma unroll
        for (int q = 0; q < 4; ++q)
            if (q < nc)
                *(float2*)&scratch[(n0 + q) * 512 + ks * 128 + c] = make_float2(ax[q], ay[q]);
    }
    __syncthreads();
    // reduce k-splits + bias -> node features
    if (tid < 896) {
        int n = tid >> 7, c = tid & 127;
        const float* P = scratch + n * 512 + c;
        float s = P[0] + P[128] + P[256] + P[384];
        const float* b2 = (n == 0) ? lb2 : (n == 1) ? mb2 : (n <= 5) ? jb2 : hb2;
        node_[n][c] = s + b2[c];
    }
    __syncthreads();

    // ---- P3: two ARMA layers, read-once matmuls with 8-way k-split
    const float* Wi = a1Wi; const float* Wr = a1Wr; const float* bb = a1b;
    #pragma unroll 1
    for (int layer = 0; layer < 2; ++layer) {
        {
            int mat = tid >> 9;                          // 0: Wi, 1: Wr (wave-uniform)
            int w   = (tid >> 6) & 7;
            int cg  = (lane & 31) | ((w & 1) << 5);      // 0..63 col-pairs
            int c   = cg * 2;
            int ks  = (lane >> 5) | ((w >> 1) << 1);     // 0..7, bit0 inside wave
            int k0  = ks * 16;
            const float* W = mat ? Wr : Wi;
            float ax[7], ay[7];
            #pragma unroll
            for (int n = 0; n < 7; ++n) { ax[n] = 0.f; ay[n] = 0.f; }
            #pragma unroll 4
            for (int kk = 0; kk < 16; kk += 2) {
                int k = k0 + kk;
                float2 w0 = *(const float2*)&W[k * 128 + c];
                float2 w1 = *(const float2*)&W[(k + 1) * 128 + c];
                #pragma unroll
                for (int n = 0; n < 7; ++n) {
                    float2 nv = *(const float2*)&node_[n][k];
                    ax[n] = fmaf(nv.x, w0.x, ax[n]); ay[n] = fmaf(nv.x, w0.y, ay[n]);
                    ax[n] = fmaf(nv.y, w1.x, ax[n]); ay[n] = fmaf(nv.y, w1.y, ay[n]);
                }
            }
            // fold ks-bit0 (lane^32 partner has same cols, adjacent k-split)
            #pragma unroll
            for (int n = 0; n < 7; ++n) {
                ax[n] += __shfl_xor(ax[n], 32);
                ay[n] += __shfl_xor(ay[n], 32);
            }
            if (lane < 32) {
                int ks4 = w >> 1;                        // 0..3 remaining splits
                float* P = scratch + (mat * 4 + ks4) * 896 + c;
                #pragma unroll
                for (int n = 0; n < 7; ++n)
                    *(float2*)&P[n * 128] = make_float2(ax[n], ay[n]);
            }
        }
        __syncthreads();
        // reduce remaining 4 k-splits -> t1 / t2
        for (int i = tid; i < 1792; i += TPB) {
            int mat = i / 896, r = i - mat * 896;
            int n = r >> 7, c = r & 127;
            const float* P = scratch + mat * 3584 + n * 128 + c;
            float s = P[0] + P[896] + P[1792] + P[2688];
            if (mat == 0) t1[n][c] = s; else t2[n][c] = s;
        }
        __syncthreads();
        // edge aggregation + residual + bias + relu
        if (tid < 896) {
            int n = tid >> 7, c = tid & 127;
            float agg = 0.0f;
            #pragma unroll
            for (int e = 0; e < 14; ++e)
                if (edst[e] == n) agg = fmaf(nrm[e], t1[esrc[e]][c], agg);
            node_[n][c] = fmaxf(agg + t2[n][c] + bb[c], 0.0f);
        }
        Wi = a2Wi; Wr = a2Wr; bb = a2b;
        __syncthreads();
    }

    // ---- P4: global max pool over the 7 nodes
    if (tid < 128) {
        float m = node_[0][tid];
        #pragma unroll
        for (int n = 1; n < 7; ++n) m = fmaxf(m, node_[n][tid]);
        pooled[tid] = m;
    }
    __syncthreads();

    // ---- P5: classifier. cW1 read-once, 16-way k-split
    {
        int j  = lane;
        int ks = tid >> 6;
        float s = 0.0f;
        #pragma unroll
        for (int kk = 0; kk < 8; ++kk) {
            int k = ks * 8 + kk;
            s = fmaf(pooled[k], cW1[k * 64 + j], s);
        }
        scratch[ks * 64 + j] = s;
    }
    __syncthreads();
    if (tid < 64) {
        float s = cb1[tid];
        #pragma unroll
        for (int q = 0; q < 16; ++q) s += scratch[q * 64 + tid];
        float v = fmaxf(s, 0.0f) * cW2[tid];
        #pragma unroll
        for (int off = 32; off > 0; off >>= 1) v += __shfl_down(v, off);
        if (tid == 0) out[0] = v + cb2[0];
    }
}

extern "C" void kernel_launch(void* const* d_in, const int* in_sizes, int n_in,
                              void* d_out, int out_size, void* d_ws, size_t ws_size,
                              hipStream_t stream) {
    (void)in_sizes; (void)n_in; (void)out_size; (void)d_ws; (void)ws_size;
    const float* x    = (const float*)d_in[0];
    const float* lW1  = (const float*)d_in[1];
    const float* lb1  = (const float*)d_in[2];
    const float* lW2  = (const float*)d_in[3];
    const float* lb2  = (const float*)d_in[4];
    const float* mW1  = (const float*)d_in[5];
    const float* mb1  = (const float*)d_in[6];
    const float* mW2  = (const float*)d_in[7];
    const float* mb2  = (const float*)d_in[8];
    const float* jW1  = (const float*)d_in[9];
    const float* jb1  = (const float*)d_in[10];
    const float* jW2  = (const float*)d_in[11];
    const float* jb2  = (const float*)d_in[12];
    const float* hW1  = (const float*)d_in[13];
    const float* hb1  = (const float*)d_in[14];
    const float* hW2  = (const float*)d_in[15];
    const float* hb2  = (const float*)d_in[16];
    const float* a1Wi = (const float*)d_in[17];
    const float* a1Wr = (const float*)d_in[18];
    const float* a1b  = (const float*)d_in[19];
    const float* a2Wi = (const float*)d_in[20];
    const float* a2Wr = (const float*)d_in[21];
    const float* a2b  = (const float*)d_in[22];
    const float* cW1  = (const float*)d_in[23];
    const float* cb1  = (const float*)d_in[24];
    const float* cW2  = (const float*)d_in[25];
    const float* cb2  = (const float*)d_in[26];
    const int*   eidx = (const int*)d_in[27];
    float* out = (float*)d_out;

    gnn_fused<<<1, TPB, 0, stream>>>(x,
        lW1, lb1, lW2, lb2, mW1, mb1, mW2, mb2,
        jW1, jb1, jW2, jb2, hW1, hb1, hW2, hb2,
        a1Wi, a1Wr, a1b, a2Wi, a2Wr, a2b,
        cW1, cb1, cW2, cb2, eidx, out);
}